// Round 2
// baseline (2018.398 us; speedup 1.0000x reference)
//
#include <hip/hip_runtime.h>
#include <hip/hip_bf16.h>

typedef __attribute__((ext_vector_type(8))) short bf16x8;
typedef __attribute__((ext_vector_type(4))) float f32x4;
typedef __attribute__((ext_vector_type(4))) unsigned short u16x4;
typedef __attribute__((ext_vector_type(8))) unsigned short u16x8;
typedef unsigned short u16;

#define DEV static __device__ __forceinline__

DEV float bf2f(u16 u) {
  union { unsigned int i; float f; } c; c.i = ((unsigned int)u) << 16; return c.f;
}
DEV u16 f2bf(float f) {
  union { float f; unsigned int i; } c; c.f = f;
  unsigned int i = c.i;
  i += 0x7FFFu + ((i >> 16) & 1u);   // RNE
  return (u16)(i >> 16);
}

DEV void gload_lds16(const void* g, void* l) {
  __builtin_amdgcn_global_load_lds((const __attribute__((address_space(1))) void*)g,
                                   (__attribute__((address_space(3))) void*)l, 16, 0, 0);
}

DEV f32x4 mfma16(bf16x8 a, bf16x8 b, f32x4 c) {
  return __builtin_amdgcn_mfma_f32_16x16x32_bf16(a, b, c, 0, 0, 0);
}

// -------- transpose+convert [Lb, K, N] fp32 -> [Lb, N, K] bf16 (K,N mult of 32) --------
__global__ __launch_bounds__(256) void ktranspose(const float* __restrict__ in, u16* __restrict__ out,
                                                  int K, int N) {
  __shared__ u16 tile[32][33];
  const float* src = in + (size_t)blockIdx.z * K * N;
  u16* dst = out + (size_t)blockIdx.z * K * N;
  const int n0 = blockIdx.x * 32, k0 = blockIdx.y * 32;
  const int tx = threadIdx.x, ty = threadIdx.y;
#pragma unroll
  for (int i = ty; i < 32; i += 8) tile[i][tx] = f2bf(src[(size_t)(k0 + i) * N + n0 + tx]);
  __syncthreads();
#pragma unroll
  for (int i = ty; i < 32; i += 8) dst[(size_t)(n0 + i) * K + k0 + tx] = tile[tx][i];
}

// -------- fp32 -> bf16 flat convert --------
__global__ __launch_bounds__(256) void kcvt(const float* __restrict__ in, u16* __restrict__ out, int n) {
  int i = blockIdx.x * 256 + threadIdx.x;
  if (i < n) out[i] = f2bf(in[i]);
}

// -------- cond MLP: h[b,0,:] = silu(cond@w1+b1)@w2 + b2 (all fp32 in) --------
__global__ __launch_bounds__(256) void kcond(const float* __restrict__ cond, const float* __restrict__ w1,
                                             const float* __restrict__ b1, const float* __restrict__ w2,
                                             const float* __restrict__ b2, float* __restrict__ h) {
  __shared__ float xr[512];
  __shared__ float t1[512];
  const int b = blockIdx.x, tid = threadIdx.x;
  for (int i = tid; i < 512; i += 256) xr[i] = cond[b * 512 + i];
  __syncthreads();
  for (int j = tid; j < 512; j += 256) {
    float acc = b1[j];
    for (int k = 0; k < 512; ++k) acc += xr[k] * w1[k * 512 + j];
    t1[j] = acc / (1.f + __expf(-acc));  // silu
  }
  __syncthreads();
  for (int j = tid; j < 512; j += 256) {
    float acc = b2[j];
    for (int k = 0; k < 512; ++k) acc += t1[k] * w2[k * 512 + j];
    h[(size_t)b * 256 * 512 + j] = acc;
  }
}

// -------- embedding: h[b,1+t,:] = emb[tok] + pos[t] (fp32 in, fp32 out) --------
__global__ __launch_bounds__(256) void kembed(const int* __restrict__ tok, const float* __restrict__ emb,
                                              const float* __restrict__ pos, float* __restrict__ h) {
  const int idx = blockIdx.x;            // b*255 + t
  const int b = idx / 255, t = idx % 255;
  const int c = threadIdx.x * 2;
  const int tk = tok[idx];
  float2 ev = *(const float2*)(emb + (size_t)tk * 512 + c);
  float2 pv = *(const float2*)(pos + (size_t)t * 512 + c);
  float2 r;
  r.x = ev.x + pv.x;
  r.y = ev.y + pv.y;
  *(float2*)(h + ((size_t)b * 256 + 1 + t) * 512 + c) = r;
}

// -------- LayerNorm: fp32 h row -> bf16 out row (fp32 g/b) --------
__global__ __launch_bounds__(64) void kln(const float* __restrict__ hin, const float* __restrict__ g,
                                          const float* __restrict__ bt, u16* __restrict__ out) {
  const int row = blockIdx.x, lane = threadIdx.x;
  const float4* x = (const float4*)(hin + (size_t)row * 512);
  float4 v0 = x[lane], v1 = x[lane + 64];
  float s1 = v0.x + v0.y + v0.z + v0.w + v1.x + v1.y + v1.z + v1.w;
  float s2 = v0.x * v0.x + v0.y * v0.y + v0.z * v0.z + v0.w * v0.w +
             v1.x * v1.x + v1.y * v1.y + v1.z * v1.z + v1.w * v1.w;
#pragma unroll
  for (int off = 1; off < 64; off <<= 1) { s1 += __shfl_xor(s1, off); s2 += __shfl_xor(s2, off); }
  float mu = s1 * (1.f / 512.f);
  float var = s2 * (1.f / 512.f) - mu * mu;
  float rs = rsqrtf(var + 1e-5f);
  const int c0 = lane * 4;
  float4 g0 = *(const float4*)(g + c0), g1 = *(const float4*)(g + 256 + c0);
  float4 b0 = *(const float4*)(bt + c0), b1 = *(const float4*)(bt + 256 + c0);
  u16x4 o0, o1;
  o0[0] = f2bf((v0.x - mu) * rs * g0.x + b0.x);
  o0[1] = f2bf((v0.y - mu) * rs * g0.y + b0.y);
  o0[2] = f2bf((v0.z - mu) * rs * g0.z + b0.z);
  o0[3] = f2bf((v0.w - mu) * rs * g0.w + b0.w);
  o1[0] = f2bf((v1.x - mu) * rs * g1.x + b1.x);
  o1[1] = f2bf((v1.y - mu) * rs * g1.y + b1.y);
  o1[2] = f2bf((v1.z - mu) * rs * g1.z + b1.z);
  o1[3] = f2bf((v1.w - mu) * rs * g1.w + b1.w);
  *(u16x4*)(out + (size_t)row * 512 + c0) = o0;
  *(u16x4*)(out + (size_t)row * 512 + 256 + c0) = o1;
}

// -------- GEMM: C[M,N] = A[M,K](bf16) @ Bt[N,K](bf16)^T (+bias fp32, epilogue) --------
// MODE 0: store bf16   MODE 1: gelu, store bf16
// MODE 2: h(fp32) +=   MODE 3: logits store fp32 (skip s==0 rows, col<515)
template<int MODE>
__global__ __launch_bounds__(256, 2) void kgemm(const u16* __restrict__ A, const u16* __restrict__ Bt,
                                                const float* __restrict__ bias, void* __restrict__ Cout,
                                                int M, int N, int K) {
  __shared__ __align__(16) u16 As[2][4096];
  __shared__ __align__(16) u16 Bs[2][4096];
  const int tid = threadIdx.x;
  const int lane = tid & 63;
  const int wr = tid >> 7, wc = (tid >> 6) & 1;           // 2x2 waves, 64x64 each
  const int m0 = blockIdx.x * 128, n0 = blockIdx.y * 128;
  const int nkt = K >> 5;
  const int Kb = K * 2;

  const int c0 = tid * 16;                                 // byte offset in 8KB tile
  const int ar0 = c0 >> 6, ao0 = c0 & 63;
  const int ar1 = (c0 + 4096) >> 6, ao1 = (c0 + 4096) & 63;
  int br0 = n0 + ar0, br1 = n0 + ar1;
  if (MODE == 3) { br0 = min(br0, N - 1); br1 = min(br1, N - 1); }
  const char* Ab = (const char*)A;
  const char* Bb = (const char*)Bt;
  const size_t a0 = (size_t)(m0 + ar0) * Kb + ao0;
  const size_t a1 = (size_t)(m0 + ar1) * Kb + ao1;
  const size_t b0 = (size_t)br0 * Kb + ao0;
  const size_t b1 = (size_t)br1 * Kb + ao1;

  f32x4 acc[4][4];
#pragma unroll
  for (int i = 0; i < 4; ++i)
#pragma unroll
    for (int j = 0; j < 4; ++j) acc[i][j] = f32x4{0.f, 0.f, 0.f, 0.f};

  gload_lds16(Ab + a0, (char*)As[0] + c0);
  gload_lds16(Ab + a1, (char*)As[0] + c0 + 4096);
  gload_lds16(Bb + b0, (char*)Bs[0] + c0);
  gload_lds16(Bb + b1, (char*)Bs[0] + c0 + 4096);
  __syncthreads();

  const int aoff = (wr * 64 + (lane & 15)) * 32 + (lane >> 4) * 8;
  const int boff = (wc * 64 + (lane & 15)) * 32 + (lane >> 4) * 8;

  int buf = 0;
  for (int kt = 0; kt < nkt; ++kt) {
    if (kt + 1 < nkt) {
      const size_t ko = (size_t)(kt + 1) * 64;
      gload_lds16(Ab + a0 + ko, (char*)As[buf ^ 1] + c0);
      gload_lds16(Ab + a1 + ko, (char*)As[buf ^ 1] + c0 + 4096);
      gload_lds16(Bb + b0 + ko, (char*)Bs[buf ^ 1] + c0);
      gload_lds16(Bb + b1 + ko, (char*)Bs[buf ^ 1] + c0 + 4096);
    }
    bf16x8 aF[4], bF[4];
#pragma unroll
    for (int mt = 0; mt < 4; ++mt) aF[mt] = *(const bf16x8*)&As[buf][aoff + mt * 512];
#pragma unroll
    for (int nt = 0; nt < 4; ++nt) bF[nt] = *(const bf16x8*)&Bs[buf][boff + nt * 512];
#pragma unroll
    for (int mt = 0; mt < 4; ++mt)
#pragma unroll
      for (int nt = 0; nt < 4; ++nt)
        acc[mt][nt] = mfma16(aF[mt], bF[nt], acc[mt][nt]);
    __syncthreads();
    buf ^= 1;
  }

  float bv[4];
#pragma unroll
  for (int nt = 0; nt < 4; ++nt) {
    int col = n0 + wc * 64 + nt * 16 + (lane & 15);
    bv[nt] = (MODE == 3) ? 0.f : bias[col];
  }

  if (MODE == 0 || MODE == 1) {
    u16* C = (u16*)Cout;
#pragma unroll
    for (int mt = 0; mt < 4; ++mt)
#pragma unroll
      for (int r = 0; r < 4; ++r) {
        int row = m0 + wr * 64 + mt * 16 + (lane >> 4) * 4 + r;
        u16* cp = C + (size_t)row * N + n0 + wc * 64 + (lane & 15);
#pragma unroll
        for (int nt = 0; nt < 4; ++nt) {
          float v = acc[mt][nt][r] + bv[nt];
          if (MODE == 1) v = 0.5f * v * (1.f + erff(v * 0.70710678118f));
          cp[nt * 16] = f2bf(v);
        }
      }
  } else if (MODE == 2) {
    float* hC = (float*)Cout;
#pragma unroll
    for (int mt = 0; mt < 4; ++mt)
#pragma unroll
      for (int r = 0; r < 4; ++r) {
        int row = m0 + wr * 64 + mt * 16 + (lane >> 4) * 4 + r;
        float* hp = hC + (size_t)row * N + n0 + wc * 64 + (lane & 15);
#pragma unroll
        for (int nt = 0; nt < 4; ++nt) hp[nt * 16] += acc[mt][nt][r] + bv[nt];
      }
  } else {
    float* C = (float*)Cout;
#pragma unroll
    for (int mt = 0; mt < 4; ++mt)
#pragma unroll
      for (int r = 0; r < 4; ++r) {
        int row = m0 + wr * 64 + mt * 16 + (lane >> 4) * 4 + r;
        int s = row & 255;
        if (s == 0) continue;
        int bb = row >> 8;
        float* cp = C + ((size_t)bb * 255 + (s - 1)) * 515 + n0 + wc * 64 + (lane & 15);
#pragma unroll
        for (int nt = 0; nt < 4; ++nt) {
          int col = n0 + wc * 64 + nt * 16 + (lane & 15);
          if (col < 515) cp[nt * 16] = acc[mt][nt][r];
        }
      }
  }
}

// -------- attention: per (b,h) block, 4 waves x 64 q-rows, two-pass softmax --------
__global__ __launch_bounds__(256, 1) void kattn(const u16* __restrict__ qkv, u16* __restrict__ o) {
  __shared__ __align__(16) u16 Ks[256][72];   // K  [t][d], padded
  __shared__ __align__(16) u16 Vt[64][264];   // V^T [d][t], padded
  __shared__ __align__(16) u16 Ps[4][64][72]; // per-wave P tile
  const int tid = threadIdx.x, wv = tid >> 6, lane = tid & 63;
  const int bh = blockIdx.x, bb = bh >> 3, hh = bh & 7;
  const size_t base = (size_t)bb * 256 * 1536 + hh * 64;

  for (int c = tid; c < 2048; c += 256) {
    int s = c >> 3, pp = c & 7;
    u16x8 kv = *(const u16x8*)(qkv + base + (size_t)s * 1536 + 512 + pp * 8);
    *(u16x8*)&Ks[s][pp * 8] = kv;
    u16x8 vv = *(const u16x8*)(qkv + base + (size_t)s * 1536 + 1024 + pp * 8);
#pragma unroll
    for (int j = 0; j < 8; ++j) Vt[pp * 8 + j][s] = vv[j];
  }
  __syncthreads();

  bf16x8 qf[4][2];
#pragma unroll
  for (int mt = 0; mt < 4; ++mt)
#pragma unroll
    for (int ks = 0; ks < 2; ++ks)
      qf[mt][ks] = *(const bf16x8*)(qkv + base +
                   (size_t)(wv * 64 + mt * 16 + (lane & 15)) * 1536 + ks * 32 + (lane >> 4) * 8);

  const float scale = 0.125f;
  float mrow[4][4], lsum[4][4];
#pragma unroll
  for (int mt = 0; mt < 4; ++mt)
#pragma unroll
    for (int r = 0; r < 4; ++r) { mrow[mt][r] = -1e30f; lsum[mt][r] = 0.f; }

  // ---- pass 1: row max ----
  for (int ct = 0; ct <= wv; ++ct) {
    f32x4 sacc[4][4];
#pragma unroll
    for (int i = 0; i < 4; ++i)
#pragma unroll
      for (int j = 0; j < 4; ++j) sacc[i][j] = f32x4{0.f, 0.f, 0.f, 0.f};
#pragma unroll
    for (int ks = 0; ks < 2; ++ks) {
      bf16x8 kf[4];
#pragma unroll
      for (int nt = 0; nt < 4; ++nt)
        kf[nt] = *(const bf16x8*)&Ks[ct * 64 + nt * 16 + (lane & 15)][ks * 32 + (lane >> 4) * 8];
#pragma unroll
      for (int mt = 0; mt < 4; ++mt)
#pragma unroll
        for (int nt = 0; nt < 4; ++nt)
          sacc[mt][nt] = mfma16(qf[mt][ks], kf[nt], sacc[mt][nt]);
    }
#pragma unroll
    for (int mt = 0; mt < 4; ++mt)
#pragma unroll
      for (int r = 0; r < 4; ++r) {
        int srow = wv * 64 + mt * 16 + (lane >> 4) * 4 + r;
        float mx = -1e30f;
#pragma unroll
        for (int nt = 0; nt < 4; ++nt) {
          int tcol = ct * 64 + nt * 16 + (lane & 15);
          float v = sacc[mt][nt][r] * scale;
          if (tcol > srow) v = -1e30f;
          mx = fmaxf(mx, v);
        }
#pragma unroll
        for (int off = 1; off < 16; off <<= 1) mx = fmaxf(mx, __shfl_xor(mx, off));
        mrow[mt][r] = fmaxf(mrow[mt][r], mx);
      }
  }

  // ---- pass 2: exp, sum, PV ----
  f32x4 oacc[4][4];
#pragma unroll
  for (int i = 0; i < 4; ++i)
#pragma unroll
    for (int j = 0; j < 4; ++j) oacc[i][j] = f32x4{0.f, 0.f, 0.f, 0.f};

  for (int ct = 0; ct <= wv; ++ct) {
    f32x4 sacc[4][4];
#pragma unroll
    for (int i = 0; i < 4; ++i)
#pragma unroll
      for (int j = 0; j < 4; ++j) sacc[i][j] = f32x4{0.f, 0.f, 0.f, 0.f};
#pragma unroll
    for (int ks = 0; ks < 2; ++ks) {
      bf16x8 kf[4];
#pragma unroll
      for (int nt = 0; nt < 4; ++nt)
        kf[nt] = *(const bf16x8*)&Ks[ct * 64 + nt * 16 + (lane & 15)][ks * 32 + (lane >> 4) * 8];
#pragma unroll
      for (int mt = 0; mt < 4; ++mt)
#pragma unroll
        for (int nt = 0; nt < 4; ++nt)
          sacc[mt][nt] = mfma16(qf[mt][ks], kf[nt], sacc[mt][nt]);
    }
#pragma unroll
    for (int mt = 0; mt < 4; ++mt)
#pragma unroll
      for (int r = 0; r < 4; ++r) {
        int srow = wv * 64 + mt * 16 + (lane >> 4) * 4 + r;
        float ps = 0.f;
#pragma unroll
        for (int nt = 0; nt < 4; ++nt) {
          int tcol = ct * 64 + nt * 16 + (lane & 15);
          float v = sacc[mt][nt][r] * scale;
          float pe = (tcol > srow) ? 0.f : __expf(v - mrow[mt][r]);
          ps += pe;
          Ps[wv][mt * 16 + (lane >> 4) * 4 + r][nt * 16 + (lane & 15)] = f2bf(pe);
        }
#pragma unroll
        for (int off = 1; off < 16; off <<= 1) ps += __shfl_xor(ps, off);
        lsum[mt][r] += ps;
      }
#pragma unroll
    for (int ks = 0; ks < 2; ++ks) {
      bf16x8 pf[4], vf[4];
#pragma unroll
      for (int mt = 0; mt < 4; ++mt)
        pf[mt] = *(const bf16x8*)&Ps[wv][mt * 16 + (lane & 15)][ks * 32 + (lane >> 4) * 8];
#pragma unroll
      for (int nt = 0; nt < 4; ++nt)
        vf[nt] = *(const bf16x8*)&Vt[nt * 16 + (lane & 15)][ct * 64 + ks * 32 + (lane >> 4) * 8];
#pragma unroll
      for (int mt = 0; mt < 4; ++mt)
#pragma unroll
        for (int nt = 0; nt < 4; ++nt)
          oacc[mt][nt] = mfma16(pf[mt], vf[nt], oacc[mt][nt]);
    }
  }

#pragma unroll
  for (int mt = 0; mt < 4; ++mt)
#pragma unroll
    for (int r = 0; r < 4; ++r) {
      int s = wv * 64 + mt * 16 + (lane >> 4) * 4 + r;
      float inv = 1.f / lsum[mt][r];
      u16* op = o + ((size_t)bb * 256 + s) * 512 + hh * 64 + (lane & 15);
#pragma unroll
      for (int nt = 0; nt < 4; ++nt) op[nt * 16] = f2bf(oacc[mt][nt][r] * inv);
    }
}

// ============================== host ==============================
extern "C" void kernel_launch(void* const* d_in, const int* in_sizes, int n_in,
                              void* d_out, int out_size, void* d_ws, size_t ws_size,
                              hipStream_t stream) {
  const int* tokens = (const int*)d_in[0];
  const float* cond = (const float*)d_in[1];
  const float* emb = (const float*)d_in[2];
  const float* pos = (const float*)d_in[3];
  const float* cw1 = (const float*)d_in[4];
  const float* cb1 = (const float*)d_in[5];
  const float* cw2 = (const float*)d_in[6];
  const float* cb2 = (const float*)d_in[7];
  const float* ln1g = (const float*)d_in[8];
  const float* ln1b = (const float*)d_in[9];
  const float* qkvw = (const float*)d_in[10];
  const float* qkvb = (const float*)d_in[11];
  const float* projw = (const float*)d_in[12];
  const float* projb = (const float*)d_in[13];
  const float* ln2g = (const float*)d_in[14];
  const float* ln2b = (const float*)d_in[15];
  const float* w1 = (const float*)d_in[16];
  const float* b1 = (const float*)d_in[17];
  const float* w2 = (const float*)d_in[18];
  const float* b2 = (const float*)d_in[19];
  const float* lnfg = (const float*)d_in[20];
  const float* lnfb = (const float*)d_in[21];

  const size_t NEEDED = (size_t)16384 * 512 * 4     // h fp32
                      + (size_t)16384 * 512 * 2     // xln
                      + (size_t)16384 * 2048 * 2    // big (qkv | mlp hidden; tail = attn_o; embB at end)
                      + (size_t)8 * 1536 * 512 * 2  // qkvT
                      + (size_t)8 * 512 * 512 * 2   // projT
                      + (size_t)8 * 2048 * 512 * 2  // w1T
                      + (size_t)8 * 512 * 2048 * 2; // w2T
  if (ws_size < NEEDED) return;

  char* p = (char*)d_ws;
  float* h = (float*)p;        p += (size_t)16384 * 512 * 4;
  u16* xln = (u16*)p;          p += (size_t)16384 * 512 * 2;
  u16* big = (u16*)p;          p += (size_t)16384 * 2048 * 2;
  u16* attn_o = big + (size_t)16384 * 1536;
  u16* embB = big;             // reused for converted emb at logits time
  u16* qkvT = (u16*)p;         p += (size_t)8 * 1536 * 512 * 2;
  u16* projT = (u16*)p;        p += (size_t)8 * 512 * 512 * 2;
  u16* w1T = (u16*)p;          p += (size_t)8 * 2048 * 512 * 2;
  u16* w2T = (u16*)p;          p += (size_t)8 * 512 * 2048 * 2;

  // transpose+convert all weights [L,K,N] fp32 -> [L,N,K] bf16
  ktranspose<<<dim3(48, 16, 8), dim3(32, 8), 0, stream>>>(qkvw, qkvT, 512, 1536);
  ktranspose<<<dim3(16, 16, 8), dim3(32, 8), 0, stream>>>(projw, projT, 512, 512);
  ktranspose<<<dim3(64, 16, 8), dim3(32, 8), 0, stream>>>(w1, w1T, 512, 2048);
  ktranspose<<<dim3(16, 64, 8), dim3(32, 8), 0, stream>>>(w2, w2T, 2048, 512);

  kembed<<<16320, 256, 0, stream>>>(tokens, emb, pos, h);
  kcond<<<64, 256, 0, stream>>>(cond, cw1, cb1, cw2, cb2, h);

  for (int l = 0; l < 8; ++l) {
    kln<<<16384, 64, 0, stream>>>(h, ln1g + l * 512, ln1b + l * 512, xln);
    kgemm<0><<<dim3(128, 12), 256, 0, stream>>>(xln, qkvT + (size_t)l * 1536 * 512,
                                                qkvb + l * 1536, big, 16384, 1536, 512);
    kattn<<<512, 256, 0, stream>>>(big, attn_o);
    kgemm<2><<<dim3(128, 4), 256, 0, stream>>>(attn_o, projT + (size_t)l * 512 * 512,
                                               projb + l * 512, h, 16384, 512, 512);
    kln<<<16384, 64, 0, stream>>>(h, ln2g + l * 512, ln2b + l * 512, xln);
    kgemm<1><<<dim3(128, 16), 256, 0, stream>>>(xln, w1T + (size_t)l * 2048 * 512,
                                                b1 + l * 2048, big, 16384, 2048, 512);
    kgemm<2><<<dim3(128, 4), 256, 0, stream>>>(big, w2T + (size_t)l * 512 * 2048,
                                               b2 + l * 512, h, 16384, 512, 2048);
  }
  kln<<<16384, 64, 0, stream>>>(h, lnfg, lnfb, xln);
  kcvt<<<1030, 256, 0, stream>>>(emb, embB, 515 * 512);   // big region is free now
  kgemm<3><<<dim3(128, 5), 256, 0, stream>>>(xln, embB, nullptr, d_out, 16384, 515, 512);
}